// Round 10
// baseline (98.202 us; speedup 1.0000x reference)
//
#include <hip/hip_runtime.h>
#include <hip/hip_bf16.h>

#define BATCH 16
#define SEQ   2048
#define DK    128
#define NT    16                    // steps per segment (512 kv / 32)
#define SC2   0.12751744f           // (1/sqrt(128)) * log2(e) -- folded into K prepass
#define THRL2 11.541560f            // defer-max threshold (= 8*log2e)

typedef __attribute__((ext_vector_type(8)))  short short8v;
typedef __attribute__((ext_vector_type(4)))  float float4v;
typedef __attribute__((ext_vector_type(16))) float float16v;

typedef const __attribute__((address_space(1))) unsigned int* gas_t;
typedef __attribute__((address_space(3))) unsigned int* las_t;

__device__ inline void gl_lds16(const void* g, void* l) {
    __builtin_amdgcn_global_load_lds((gas_t)g, (las_t)l, 16, 0, 0);
}

__device__ inline short f2bf(float f) {
    __hip_bfloat16 h = __float2bfloat16(f);
    unsigned short u;
    __builtin_memcpy(&u, &h, sizeof(u));
    return (short)u;
}

__device__ inline unsigned cvt_pk_bf16(float a, float b) {
    unsigned r;
    asm("v_cvt_pk_bf16_f32 %0, %1, %2" : "=v"(r) : "v"(a), "v"(b));
    return r;   // lo = bf16(a), hi = bf16(b)
}

// -------- prepass: K fp32 -> bf16 * (scale*log2e)  (row-major) --------
__global__ __launch_bounds__(256)
void conv_k_kernel(const float* __restrict__ k, short* __restrict__ kb)
{
    size_t i = ((size_t)blockIdx.x * 256 + threadIdx.x) * 8;
    float4 a = *reinterpret_cast<const float4*>(k + i);
    float4 b = *reinterpret_cast<const float4*>(k + i + 4);
    short8v t;
    t[0] = f2bf(a.x * SC2); t[1] = f2bf(a.y * SC2); t[2] = f2bf(a.z * SC2); t[3] = f2bf(a.w * SC2);
    t[4] = f2bf(b.x * SC2); t[5] = f2bf(b.y * SC2); t[6] = f2bf(b.z * SC2); t[7] = f2bf(b.w * SC2);
    *reinterpret_cast<short8v*>(kb + i) = t;
}

// -------- prepass: V fp32 [b][s][d] -> bf16 Vt [b][d][col] ------------
// psi-interleave per 16-kv group: V[kv] stored at col = base16 | pos,
// pos = 8*((kv>>2)&1) + 4*((kv>>3)&1) + (kv&3): 32x32-MFMA PV A-frag
// (packed P regs) matches contiguous 16B B-fragment units.
__global__ __launch_bounds__(256)
void transpose_v_kernel(const float* __restrict__ v, short* __restrict__ vt)
{
    __shared__ float tile[32][33];
    const int tx = threadIdx.x & 31;
    const int ty = threadIdx.x >> 5;              // 0..7
    const int b  = blockIdx.z;
    const int s0 = blockIdx.x * 32;
    const int d0 = blockIdx.y * 32;

    const float* vb = v + ((size_t)b * SEQ + s0) * DK + d0;
#pragma unroll
    for (int i = 0; i < 4; ++i) {
        int r = ty + 8 * i;
        tile[r][tx] = vb[(size_t)r * DK + tx];
    }
    __syncthreads();

    const int s   = s0 + tx;
    const int kvl = s & 15;
    const int pos = (((kvl >> 2) & 1) << 3) | (((kvl >> 3) & 1) << 2) | (kvl & 3);
    const size_t col = (size_t)(s & ~15) | pos;

    short* vtb = vt + ((size_t)b * DK + d0) * SEQ;
#pragma unroll
    for (int i = 0; i < 4; ++i) {
        int r = ty + 8 * i;                       // d offset
        vtb[(size_t)r * SEQ + col] = f2bf(tile[tx][r]);
    }
}

// ---------------- main: dual q-tile flash attention -------------------
// Grid 256 (XCD-decoded: each XCD owns 2 batches -> staging is L2-local,
// FETCH == compulsory, r8-verified).  Block = 512 thr = 8 waves:
// qw = wave&1 (64 q rows = TWO 32x32 q-tiles), h = wave>>1 (kv seg of 512).
// Each K/V LDS fragment read feeds BOTH q-tiles' MFMAs -> ds_read_b128
// per MFMA = 0.5 (was 1.0); 16 steps/block (was 32) -> half the barriers.
// LDS: 2buf x 4seg x (K 8KB | V 8KB) = 128KB staging (+2KB merge m/l).
// Staging: wave 2h stages K(seg h), wave 2h+1 stages V(seg h); 8 gl_lds ea.
// Per-seg tile geometry identical to r8 (KVBLK=32; K [32][256B] slot^=(kr&15);
// V d-pair packed [64 R][128B] unit w = ((d&1)<<2|u)^(R&7), psi-ordered).
// Epilogue: 2-round LDS merge tree over the 4 segments, then h=0 writes.
// __launch_bounds__(512,2): natural ~240 VGPR fits 2 waves/SIMD; do NOT
// request more (r7: ",4" forced 64-VGPR target -> full spill, 2.4x slower).
__global__ __launch_bounds__(512, 2)
void attn_fwd_v10(const float* __restrict__ q,
                  const short* __restrict__ kb,
                  const short* __restrict__ vt,
                  float* __restrict__ out)
{
    __shared__ __align__(16) char lds[133120];   // 2x64KB staging; merge aliases + 2KB m/l

    const int tid  = threadIdx.x;
    const int lane = tid & 63;
    const int wave = tid >> 6;         // 0..7
    const int qw   = wave & 1;         // q sub-block (64 rows)
    const int h    = wave >> 1;        // kv segment 0..3
    const int bid  = blockIdx.x;
    const int work = (bid & 7) * 32 + (bid >> 3);   // XCD-grouped
    const int b    = work >> 4;
    const int q0   = (work & 15) * 128 + qw * 64;

    const int l31 = lane & 31;
    const int hi  = lane >> 5;

    // ---- Q fragments for both tiles: qfX[s] = Q[qrow][s*16 + hi*8 + 0..7] ----
    short8v qf0[8], qf1[8];
    {
        const float* qr0 = q + ((size_t)b * SEQ + q0 + l31) * DK + hi * 8;
        const float* qr1 = qr0 + 32 * DK;
#pragma unroll
        for (int s = 0; s < 8; ++s) {
            float4 x = *reinterpret_cast<const float4*>(qr0 + s * 16);
            float4 y = *reinterpret_cast<const float4*>(qr0 + s * 16 + 4);
            union { unsigned u[4]; short8v v; } pk;
            pk.u[0] = cvt_pk_bf16(x.x, x.y);
            pk.u[1] = cvt_pk_bf16(x.z, x.w);
            pk.u[2] = cvt_pk_bf16(y.x, y.y);
            pk.u[3] = cvt_pk_bf16(y.z, y.w);
            qf0[s] = pk.v;
            x = *reinterpret_cast<const float4*>(qr1 + s * 16);
            y = *reinterpret_cast<const float4*>(qr1 + s * 16 + 4);
            pk.u[0] = cvt_pk_bf16(x.x, x.y);
            pk.u[1] = cvt_pk_bf16(x.z, x.w);
            pk.u[2] = cvt_pk_bf16(y.x, y.y);
            pk.u[3] = cvt_pk_bf16(y.z, y.w);
            qf1[s] = pk.v;
        }
    }

    const char* kB = (const char*)(kb + (size_t)b * SEQ * DK);   // 256B rows
    const char* vB = (const char*)(vt + (size_t)b * DK * SEQ);   // 4096B rows

    float mA = -1e30f, lA = 0.0f;
    float mB = -1e30f, lB = 0.0f;
    float16v o0[4], o1[4];
#pragma unroll
    for (int dblk = 0; dblk < 4; ++dblk)
#pragma unroll
        for (int i = 0; i < 16; ++i) { o0[dblk][i] = 0.f; o1[dblk][i] = 0.f; }

    // ---- staging: wave 2h -> K(seg h), wave 2h+1 -> V(seg h); 8 x 1KB ----
    auto STAGE = [&](int bufsel, int t) {
        char* base = lds + bufsel * 65536 + h * 16384;
        if (qw == 0) {
            const char* ksrc = kB + (size_t)(h * 512 + t * 32) * 256;
#pragma unroll
            for (int i = 0; i < 8; ++i) {
                const int kr = i * 4 + (lane >> 4);           // kv row 0..31
                gl_lds16(ksrc + (size_t)kr * 256
                              + (((lane & 15) ^ ((i & 3) << 2) ^ (lane >> 4)) << 4),
                         base + i * 1024);
            }
        } else {
            const char* vsrc = vB + (size_t)h * 1024 + (size_t)t * 64;
            const int unit = (lane & 7) ^ (lane >> 3);
#pragma unroll
            for (int i = 0; i < 8; ++i) {
                const int d = 16 * i + 2 * (lane >> 3) + (unit >> 2);
                gl_lds16(vsrc + (size_t)d * 4096 + (unit & 3) * 16,
                         base + 8192 + i * 1024);
            }
        }
    };

    STAGE(0, 0);
    __syncthreads();

    int buf = 0;
    for (int t = 0; t < NT; ++t) {
        if (t + 1 < NT) STAGE(buf ^ 1, t + 1);

        const char* Kl = lds + buf * 65536 + h * 16384;
        const char* Vl = Kl + 8192;
        const char* ka = Kl + l31 * 256;

        // ---- QK^T: one K-frag read feeds BOTH q-tiles ----
        float16v sa0, sa1;
#pragma unroll
        for (int i = 0; i < 16; ++i) { sa0[i] = 0.f; sa1[i] = 0.f; }
        __builtin_amdgcn_s_setprio(1);
#pragma unroll
        for (int s = 0; s < 8; ++s) {
            const int un = ((2 * s + hi) ^ (l31 & 15)) << 4;
            short8v kf = *reinterpret_cast<const short8v*>(ka + un);
            sa0 = __builtin_amdgcn_mfma_f32_32x32x16_bf16(kf, qf0[s], sa0, 0, 0, 0);
            sa1 = __builtin_amdgcn_mfma_f32_32x32x16_bf16(kf, qf1[s], sa1, 0, 0, 0);
        }
        __builtin_amdgcn_s_setprio(0);

        // ---- online softmax, tile A ----
        {
            float mx = sa0[0];
#pragma unroll
            for (int i = 1; i < 16; ++i) mx = fmaxf(mx, sa0[i]);
            mx = fmaxf(mx, __shfl_xor(mx, 32));
            if (!__all(mx <= mA + THRL2)) {
                const float mnew  = fmaxf(mA, mx);
                const float alpha = exp2f(mA - mnew);
                lA *= alpha;
                mA = mnew;
                float aq[16];
#pragma unroll
                for (int reg = 0; reg < 16; ++reg)
                    aq[reg] = __shfl(alpha, (reg & 3) + 8 * (reg >> 2) + 4 * hi);
#pragma unroll
                for (int dblk = 0; dblk < 4; ++dblk)
#pragma unroll
                    for (int reg = 0; reg < 16; ++reg) o0[dblk][reg] *= aq[reg];
            }
            float ts = 0.f;
#pragma unroll
            for (int i = 0; i < 16; ++i) {
                const float e = exp2f(sa0[i] - mA);
                sa0[i] = e;
                ts += e;
            }
            ts += __shfl_xor(ts, 32);
            lA += ts;
        }
        // ---- online softmax, tile B ----
        {
            float mx = sa1[0];
#pragma unroll
            for (int i = 1; i < 16; ++i) mx = fmaxf(mx, sa1[i]);
            mx = fmaxf(mx, __shfl_xor(mx, 32));
            if (!__all(mx <= mB + THRL2)) {
                const float mnew  = fmaxf(mB, mx);
                const float alpha = exp2f(mB - mnew);
                lB *= alpha;
                mB = mnew;
                float aq[16];
#pragma unroll
                for (int reg = 0; reg < 16; ++reg)
                    aq[reg] = __shfl(alpha, (reg & 3) + 8 * (reg >> 2) + 4 * hi);
#pragma unroll
                for (int dblk = 0; dblk < 4; ++dblk)
#pragma unroll
                    for (int reg = 0; reg < 16; ++reg) o1[dblk][reg] *= aq[reg];
            }
            float ts = 0.f;
#pragma unroll
            for (int i = 0; i < 16; ++i) {
                const float e = exp2f(sa1[i] - mB);
                sa1[i] = e;
                ts += e;
            }
            ts += __shfl_xor(ts, 32);
            lB += ts;
        }

        // ---- P -> bf16 A-fragments (psi-order) ----
        short8v pf0[2], pf1[2];
#pragma unroll
        for (int g = 0; g < 2; ++g) {
            const int r0 = g * 8;
            union { unsigned u[4]; short8v v; } pk;
            pk.u[0] = cvt_pk_bf16(sa0[r0 + 0], sa0[r0 + 1]);
            pk.u[1] = cvt_pk_bf16(sa0[r0 + 2], sa0[r0 + 3]);
            pk.u[2] = cvt_pk_bf16(sa0[r0 + 4], sa0[r0 + 5]);
            pk.u[3] = cvt_pk_bf16(sa0[r0 + 6], sa0[r0 + 7]);
            pf0[g] = pk.v;
            pk.u[0] = cvt_pk_bf16(sa1[r0 + 0], sa1[r0 + 1]);
            pk.u[1] = cvt_pk_bf16(sa1[r0 + 2], sa1[r0 + 3]);
            pk.u[2] = cvt_pk_bf16(sa1[r0 + 4], sa1[r0 + 5]);
            pk.u[3] = cvt_pk_bf16(sa1[r0 + 6], sa1[r0 + 7]);
            pf1[g] = pk.v;
        }

        // ---- PV: one V-frag read feeds BOTH q-tiles ----
        __builtin_amdgcn_s_setprio(1);
#pragma unroll
        for (int dblk = 0; dblk < 4; ++dblk) {
            const int R  = dblk * 16 + (l31 >> 1);
            const char* vr = Vl + R * 128;
            const int dh4 = (l31 & 1) << 2;
#pragma unroll
            for (int g = 0; g < 2; ++g) {
                const int w = ((dh4 | (2 * g + hi)) ^ (R & 7)) << 4;
                short8v vf = *reinterpret_cast<const short8v*>(vr + w);
                o0[dblk] = __builtin_amdgcn_mfma_f32_32x32x16_bf16(pf0[g], vf, o0[dblk], 0, 0, 0);
                o1[dblk] = __builtin_amdgcn_mfma_f32_32x32x16_bf16(pf1[g], vf, o1[dblk], 0, 0, 0);
            }
        }
        __builtin_amdgcn_s_setprio(0);

        __syncthreads();       // drains staged loads + LDS reads
        buf ^= 1;
    }

    // ---- 2-round merge tree over the 4 kv segments (aliases staging LDS) ----
    // regions: rid*32KB O-data; m/l at 131072 + rid*512B.
    auto WRITE_REGION = [&](int rid) {
        float* ro = (float*)(lds + rid * 32768);
        float* ml = (float*)(lds + 131072) + rid * 128;
#pragma unroll
        for (int dblk = 0; dblk < 4; ++dblk)
#pragma unroll
            for (int reg = 0; reg < 16; ++reg) {
                const int qp = (reg & 3) + 8 * (reg >> 2) + 4 * hi;
                ro[(qp) * 128 + dblk * 32 + l31]      = o0[dblk][reg];
                ro[(32 + qp) * 128 + dblk * 32 + l31] = o1[dblk][reg];
            }
        if (hi == 0) {
            ml[l31 * 2]          = mA;
            ml[l31 * 2 + 1]      = lA;
            ml[64 + l31 * 2]     = mB;
            ml[64 + l31 * 2 + 1] = lB;
        }
    };

    auto MERGE_FROM = [&](int rid) {
        float* ro = (float*)(lds + rid * 32768);
        float* ml = (float*)(lds + 131072) + rid * 128;
        // tile A
        {
            const float m1 = ml[l31 * 2];
            const float l1 = ml[l31 * 2 + 1];
            const float mf = fmaxf(mA, m1);
            const float a0 = exp2f(mA - mf);
            const float a1 = exp2f(m1 - mf);
            lA = lA * a0 + l1 * a1;
            mA = mf;
            float a0q[16], a1q[16];
#pragma unroll
            for (int reg = 0; reg < 16; ++reg) {
                const int qp = (reg & 3) + 8 * (reg >> 2) + 4 * hi;
                a0q[reg] = __shfl(a0, qp);
                a1q[reg] = __shfl(a1, qp);
            }
#pragma unroll
            for (int dblk = 0; dblk < 4; ++dblk)
#pragma unroll
                for (int reg = 0; reg < 16; ++reg) {
                    const int qp = (reg & 3) + 8 * (reg >> 2) + 4 * hi;
                    o0[dblk][reg] = o0[dblk][reg] * a0q[reg]
                                  + ro[qp * 128 + dblk * 32 + l31] * a1q[reg];
                }
        }
        // tile B
        {
            const float m1 = ml[64 + l31 * 2];
            const float l1 = ml[64 + l31 * 2 + 1];
            const float mf = fmaxf(mB, m1);
            const float a0 = exp2f(mB - mf);
            const float a1 = exp2f(m1 - mf);
            lB = lB * a0 + l1 * a1;
            mB = mf;
            float a0q[16], a1q[16];
#pragma unroll
            for (int reg = 0; reg < 16; ++reg) {
                const int qp = (reg & 3) + 8 * (reg >> 2) + 4 * hi;
                a0q[reg] = __shfl(a0, qp);
                a1q[reg] = __shfl(a1, qp);
            }
#pragma unroll
            for (int dblk = 0; dblk < 4; ++dblk)
#pragma unroll
                for (int reg = 0; reg < 16; ++reg) {
                    const int qp = (reg & 3) + 8 * (reg >> 2) + 4 * hi;
                    o1[dblk][reg] = o1[dblk][reg] * a0q[reg]
                                  + ro[(32 + qp) * 128 + dblk * 32 + l31] * a1q[reg];
                }
        }
    };

    // main loop ended with __syncthreads -> LDS idle, all waves aligned
    if (h == 1 || h == 3) WRITE_REGION((h >> 1) * 2 + qw);
    __syncthreads();
    if (h == 0 || h == 2) MERGE_FROM((h >> 1) * 2 + qw);
    __syncthreads();
    if (h == 2) WRITE_REGION(qw);
    __syncthreads();
    if (h == 0) {
        MERGE_FROM(qw);
        const float liA = 1.0f / lA;
        const float liB = 1.0f / lB;
        float lAq[16], lBq[16];
#pragma unroll
        for (int reg = 0; reg < 16; ++reg) {
            const int qp = (reg & 3) + 8 * (reg >> 2) + 4 * hi;
            lAq[reg] = __shfl(liA, qp);
            lBq[reg] = __shfl(liB, qp);
        }
        float* ob = out + ((size_t)b * SEQ + q0) * DK;
#pragma unroll
        for (int dblk = 0; dblk < 4; ++dblk)
#pragma unroll
            for (int reg = 0; reg < 16; ++reg) {
                const int qp = (reg & 3) + 8 * (reg >> 2) + 4 * hi;
                ob[(size_t)qp * DK + dblk * 32 + l31]        = o0[dblk][reg] * lAq[reg];
                ob[(size_t)(32 + qp) * DK + dblk * 32 + l31] = o1[dblk][reg] * lBq[reg];
            }
    }
}

// ---------------- fallback (round-1 kernel) if ws too small -----------
__global__ __launch_bounds__(256)
void attn_fwd_slow(const float* __restrict__ q,
                   const float* __restrict__ k,
                   const float* __restrict__ v,
                   float* __restrict__ out)
{
    const int lane = threadIdx.x & 63;
    const int wave = threadIdx.x >> 6;
    const int b    = blockIdx.y;
    const int q0   = blockIdx.x * 64 + wave * 16;
    const int row = lane & 15;
    const int grp = lane >> 4;

    const float* qb = q + ((size_t)b * SEQ + q0) * DK;
    const float* kbp = k + (size_t)b * SEQ * DK;
    const float* vbp = v + (size_t)b * SEQ * DK;

    short8v qf[4];
#pragma unroll
    for (int c = 0; c < 4; ++c) {
        const float* p = qb + row * DK + c * 32 + grp * 8;
        float4 x = *reinterpret_cast<const float4*>(p);
        float4 y = *reinterpret_cast<const float4*>(p + 4);
        short8v t;
        t[0] = f2bf(x.x); t[1] = f2bf(x.y); t[2] = f2bf(x.z); t[3] = f2bf(x.w);
        t[4] = f2bf(y.x); t[5] = f2bf(y.y); t[6] = f2bf(y.z); t[7] = f2bf(y.w);
        qf[c] = t;
    }

    float m_run = -1e30f, l_run = 0.0f;
    float4v o[8];
#pragma unroll
    for (int i = 0; i < 8; ++i) { o[i][0]=0.f; o[i][1]=0.f; o[i][2]=0.f; o[i][3]=0.f; }
    const float scale = 0.08838834764831845f;

    for (int kv0 = 0; kv0 < SEQ; kv0 += 16) {
        short8v kf[4];
        const float* kp0 = kbp + (size_t)(kv0 + row) * DK + grp * 8;
#pragma unroll
        for (int c = 0; c < 4; ++c) {
            const float* p = kp0 + c * 32;
            float4 x = *reinterpret_cast<const float4*>(p);
            float4 y = *reinterpret_cast<const float4*>(p + 4);
            short8v t;
            t[0] = f2bf(x.x); t[1] = f2bf(x.y); t[2] = f2bf(x.z); t[3] = f2bf(x.w);
            t[4] = f2bf(y.x); t[5] = f2bf(y.y); t[6] = f2bf(y.z); t[7] = f2bf(y.w);
            kf[c] = t;
        }
        short8v vf[8];
#pragma unroll
        for (int dblk = 0; dblk < 8; ++dblk) {
            const float* p = vbp + (size_t)(kv0 + 4 * grp) * DK + dblk * 16 + row;
            short b0 = f2bf(p[0]);
            short b1 = f2bf(p[DK]);
            short b2 = f2bf(p[2 * DK]);
            short b3 = f2bf(p[3 * DK]);
            short8v t;
            t[0]=b0; t[1]=b1; t[2]=b2; t[3]=b3; t[4]=b0; t[5]=b1; t[6]=b2; t[7]=b3;
            vf[dblk] = t;
        }
        float4v s; s[0]=0.f; s[1]=0.f; s[2]=0.f; s[3]=0.f;
#pragma unroll
        for (int c = 0; c < 4; ++c)
            s = __builtin_amdgcn_mfma_f32_16x16x32_bf16(kf[c], qf[c], s, 0, 0, 0);

        float sv[4]; float tmax = -1e30f;
#pragma unroll
        for (int r = 0; r < 4; ++r) { sv[r] = s[r] * scale; tmax = fmaxf(tmax, sv[r]); }
        tmax = fmaxf(tmax, __shfl_xor(tmax, 16));
        tmax = fmaxf(tmax, __shfl_xor(tmax, 32));
        const float mnew = fmaxf(m_run, tmax);
        float pr[4]; float tsum = 0.f;
#pragma unroll
        for (int r = 0; r < 4; ++r) { pr[r] = __expf(sv[r] - mnew); tsum += pr[r]; }
        tsum += __shfl_xor(tsum, 16);
        tsum += __shfl_xor(tsum, 32);
        const float alpha = __expf(m_run - mnew);
        l_run = l_run * alpha + tsum;
        m_run = mnew;
        float aq[4];
#pragma unroll
        for (int r = 0; r < 4; ++r) aq[r] = __shfl(alpha, grp * 4 + r);
#pragma unroll
        for (int dblk = 0; dblk < 8; ++dblk)
#pragma unroll
            for (int r = 0; r < 4; ++r) o[dblk][r] *= aq[r];

        short8v pfv;
        pfv[0]=f2bf(pr[0]); pfv[1]=f2bf(pr[1]); pfv[2]=f2bf(pr[2]); pfv[3]=f2bf(pr[3]);
        pfv[4]=0; pfv[5]=0; pfv[6]=0; pfv[7]=0;
#pragma unroll
        for (int dblk = 0; dblk < 8; ++dblk)
            o[dblk] = __builtin_amdgcn_mfma_f32_16x16x32_bf16(pfv, vf[dblk], o[dblk], 0, 0, 0);
    }

    const float linv = 1.0f / l_run;
    float li[4];
#pragma unroll
    for (int r = 0; r < 4; ++r) li[r] = __shfl(linv, grp * 4 + r);
    float* ob = out + ((size_t)b * SEQ + q0) * DK;
#pragma unroll
    for (int dblk = 0; dblk < 8; ++dblk)
#pragma unroll
        for (int r = 0; r < 4; ++r)
            ob[(size_t)(grp * 4 + r) * DK + dblk * 16 + row] = o[dblk][r] * li[r];
}

extern "C" void kernel_launch(void* const* d_in, const int* in_sizes, int n_in,
                              void* d_out, int out_size, void* d_ws, size_t ws_size,
                              hipStream_t stream) {
    const float* q = (const float*)d_in[0];
    const float* k = (const float*)d_in[1];
    const float* v = (const float*)d_in[2];
    float* out = (float*)d_out;

    const size_t kb_bytes = (size_t)BATCH * SEQ * DK * sizeof(short);
    const size_t need = 2 * kb_bytes;

    if (ws_size >= need) {
        short* kb = (short*)d_ws;
        short* vt = (short*)((char*)d_ws + kb_bytes);
        hipLaunchKernelGGL(conv_k_kernel, dim3(2048), dim3(256), 0, stream, k, kb);
        hipLaunchKernelGGL(transpose_v_kernel, dim3(SEQ / 32, DK / 32, BATCH), dim3(256), 0, stream, v, vt);
        hipLaunchKernelGGL(attn_fwd_v10, dim3((SEQ / 128) * BATCH), dim3(512), 0, stream, q, kb, vt, out);
    } else {
        hipLaunchKernelGGL(attn_fwd_slow, dim3(SEQ / 64, BATCH), dim3(256), 0, stream, q, k, v, out);
    }
}